// Round 11
// baseline (125.652 us; speedup 1.0000x reference)
//
#include <hip/hip_runtime.h>

#define NROWS 256
#define LROW  65536
#define TOT   ((size_t)NROWS * LROW)
#define BLOCK 256
#define VPT   16
#define TILE  (BLOCK * VPT)       // 4096 elements, 16KB
#define TPR   (LROW / TILE)       // 16 tiles per row
#define NTILE (NROWS * TPR)       // 4096 blocks

// out[j] = (K0 + prefix_excl(inc)[j] + 2000) / 4000
// inc[j] = stress(t[j]) * (t[j+1]-t[j]),  t = 500*x
// stress(t) = a*exp2(t*ec) + pb2*log2(1+t) + cterm
//
// Round-10 lesson: LDS-staged coalescing brought the scan 41.6 -> ~33us, but
// 4 blocks/CU left phase-serialization idle (load|barrier|scan|lookback|store
// align across co-resident blocks). This version: 8 blocks/CU (16KB tile,
// 4096 blocks) and 3 barriers instead of 5:
//  - boundary read uses wave-lockstep (same-wave LDS read before any same-wave
//    write in program order); lane63 fetches its boundary from global.
//  - every wave redundantly does the 4-elem block scan + its own lookback
//    poll, so no s_carry broadcast barrier.
// Round-5 lesson retained: RELAXED packed {flag,value} atomics only.

__device__ __forceinline__ int sw(int e) { return e ^ (((e >> 4) & 3) << 2); }

__global__ __launch_bounds__(BLOCK)
void stf_scan6(const float* __restrict__ x,
               const float* __restrict__ params,
               const float* __restrict__ k0v,
               const float* __restrict__ procc,
               float* __restrict__ out,
               unsigned long long* __restrict__ state)
{
    const int bid  = blockIdx.x;
    const int d    = bid >> 4;        // TPR = 16
    const int sub  = bid & 15;
    const int tid  = threadIdx.x;
    const int lane = tid & 63;
    const int wid  = tid >> 6;        // 0..3

    __shared__ float tile[TILE];      // 16KB, swizzled element store
    __shared__ float baseArr[BLOCK];  // 1KB
    __shared__ float wtot[4];

    // per-row constants
    const float pa  = params[d * 4 + 0];
    const float pb  = params[d * 4 + 1];
    const float pcc = params[d * 4 + 2];
    const float pd  = params[d * 4 + 3];
    const float R   = procc[d * 4 + 0];
    const float T   = procc[d * 4 + 1] + 0.1f;
    const float P   = procc[d * 4 + 2];
    const float ec    = -1.44269504f / (fabsf(pcc) + 0.001f);
    const float pb2   = pb * 0.69314718f;
    const float cterm = pd * R * P / T;
    const float k0    = k0v[d];

    const size_t tbase = (size_t)d * LROW + (size_t)sub * TILE;

    // ---- phase 1: fully coalesced global loads (lane i at +16B*i) ----
    const float* __restrict__ xp = x + tbase + tid * 4;
    float4 L0 = *(const float4*)(xp + 0 * 1024);
    float4 L1 = *(const float4*)(xp + 1 * 1024);
    float4 L2 = *(const float4*)(xp + 2 * 1024);
    float4 L3 = *(const float4*)(xp + 3 * 1024);
    // lane63 threads: boundary element from GLOBAL (their LDS boundary slot is
    // owned by a different wave -> cross-wave race if read from LDS).
    float bxg = 0.0f;
    if (lane == 63) {
        const size_t gi = tbase + (size_t)(tid + 1) * VPT;  // == tbase+TILE for last thread
        if (gi < TOT) bxg = x[gi];
    }

    // ---- phase 2: stage to LDS (swizzled) ----
    *(float4*)&tile[sw(0 * 1024 + tid * 4)] = L0;
    *(float4*)&tile[sw(1 * 1024 + tid * 4)] = L1;
    *(float4*)&tile[sw(2 * 1024 + tid * 4)] = L2;
    *(float4*)&tile[sw(3 * 1024 + tid * 4)] = L3;
    __syncthreads();                  // A: tile fully staged

    // boundary: first elem of next thread's run. For lane<63 the slot's owner
    // (tid+1) is in the SAME wave: its phase-3 writes are later in program
    // order -> lockstep-safe without a barrier. lane63 uses the global value.
    const float bnd = (lane < 63) ? tile[sw((tid + 1) * VPT)] : bxg;

    // ---- phase 3: streamed local scan; overwrite own slots with s-values ----
    // slot e=16*tid+k receives s[k] = pref[k-1] (s[0]=0); reader adds base.
    const int eb = tid * VPT;
    float4 cur = *(const float4*)&tile[sw(eb)];
    float run = 0.0f, sprev = 0.0f;
    #pragma unroll
    for (int g = 0; g < 4; ++g) {
        float4 nxt;
        if (g < 3) nxt = *(const float4*)&tile[sw(eb + 4 * (g + 1))];
        else       nxt = make_float4(bnd, 0.0f, 0.0f, 0.0f);

        const float ta = cur.x * 500.0f, tb = cur.y * 500.0f;
        const float tc = cur.z * 500.0f, td = cur.w * 500.0f;
        const float te = nxt.x * 500.0f;

        float4 s4;
        s4.x = sprev;   // s[4g]   = pref[4g-1]
        run += (pa * exp2f(ta * ec) + pb2 * __log2f(1.0f + ta) + cterm) * (tb - ta);
        s4.y = run;     // s[4g+1] = pref[4g]
        run += (pa * exp2f(tb * ec) + pb2 * __log2f(1.0f + tb) + cterm) * (tc - tb);
        s4.z = run;     // s[4g+2] = pref[4g+1]
        run += (pa * exp2f(tc * ec) + pb2 * __log2f(1.0f + tc) + cterm) * (td - tc);
        s4.w = run;     // s[4g+3] = pref[4g+2]
        run += (pa * exp2f(td * ec) + pb2 * __log2f(1.0f + td) + cterm) * (te - td);
        sprev = run;    // pref[4g+3]

        *(float4*)&tile[sw(eb + 4 * g)] = s4;   // own slots only
        cur = nxt;
    }
    // Final tile of a row computes one junk increment (bnd = next row / 0),
    // but it only feeds that tile's aggregate, which has no consumer.

    // ---- phase 4: wave inclusive scan of per-thread sums ----
    float v = run;
    #pragma unroll
    for (int off = 1; off < 64; off <<= 1) {
        const float o = __shfl_up(v, off);
        if (lane >= off) v += o;
    }
    const float waveExcl = v - run;
    if (lane == 63) wtot[wid] = v;
    __syncthreads();                  // B: wtot ready

    // ---- phase 5: redundant per-wave block scan + publish + lookback ----
    float wv = (lane < 4) ? wtot[lane] : 0.0f;
    float iv = wv;
    #pragma unroll
    for (int off = 1; off < 4; off <<= 1) {
        const float o = __shfl_up(iv, off);
        if (lane >= off && lane < 4) iv += o;
    }
    const float total    = __shfl(iv, 3);
    const float wexclOwn = __shfl(iv, wid) - __shfl(wv, wid);

    if (tid == 0) {
        const unsigned long long packed =
            0x100000000ull | (unsigned long long)__float_as_uint(total);
        // RELAXED only: flag+value share one word (round-5 lesson:
        // acquire/release at agent scope = per-XCD L2 flush storm).
        __hip_atomic_store(&state[bid], packed,
                           __ATOMIC_RELAXED, __HIP_MEMORY_SCOPE_AGENT);
    }
    // every wave polls its row-predecessors redundantly (<=15 of them)
    float c = 0.0f;
    if (lane < sub) {
        const int pt = bid - 1 - lane;
        unsigned long long w;
        for (;;) {
            w = __hip_atomic_load(&state[pt],
                                  __ATOMIC_RELAXED, __HIP_MEMORY_SCOPE_AGENT);
            if (w >> 32) break;
            __builtin_amdgcn_s_sleep(2);
        }
        c = __uint_as_float((unsigned)w);
    }
    #pragma unroll
    for (int off = 1; off < 64; off <<= 1) c += __shfl_xor(c, off);

    // ---- phase 6: per-producer base values ----
    baseArr[tid] = k0 + c + wexclOwn + waveExcl;
    __syncthreads();                  // C: baseArr ready

    // ---- phase 7: fully coalesced stores ----
    const float scl = 2.5e-4f;
    float* __restrict__ op = out + tbase + tid * 4;
    #pragma unroll
    for (int r = 0; r < 4; ++r) {
        const float4 sv = *(const float4*)&tile[sw(r * 1024 + tid * 4)];
        const float b = baseArr[r * 64 + (tid >> 2)];    // producer = e>>4
        float4 o;
        o.x = (sv.x + b) * scl + 0.5f;
        o.y = (sv.y + b) * scl + 0.5f;
        o.z = (sv.z + b) * scl + 0.5f;
        o.w = (sv.w + b) * scl + 0.5f;
        *(float4*)(op + r * 1024) = o;
    }
}

extern "C" void kernel_launch(void* const* d_in, const int* in_sizes, int n_in,
                              void* d_out, int out_size, void* d_ws, size_t ws_size,
                              hipStream_t stream) {
    const float* x      = (const float*)d_in[0];   // [256*65536]
    const float* params = (const float*)d_in[1];   // [256,4]
    const float* K0     = (const float*)d_in[2];   // [256]
    const float* procc  = (const float*)d_in[3];   // [256,4]
    float* out = (float*)d_out;
    unsigned long long* state = (unsigned long long*)d_ws;

    // d_ws is poisoned 0xAA before every launch -> flags must be cleared.
    hipMemsetAsync(d_ws, 0, NTILE * sizeof(unsigned long long), stream);
    stf_scan6<<<NTILE, BLOCK, 0, stream>>>(x, params, K0, procc, out, state);
}